// Round 5
// baseline (5983.273 us; speedup 1.0000x reference)
//
#include <hip/hip_runtime.h>
#include <hip/hip_bf16.h>

// Model_26439818674684: hierarchical LSTM forecaster.
//  - text LSTM layer 1 is DEAD (reference uses layer-0 final hidden only).
//  - input projections hoisted into bf16 MFMA GEMMs (bias folded), gate
//    buffers in [t][seq][1024] layout.
//  - recurrences: persistent kernel, block owns 32 seqs. KEY (round 5):
//    wave's 8 B-tiles = 4 gates x 2 unit-tiles, so all 4 gate values of a
//    (seq,unit) land in ONE lane's accs -> cell update is register-only.
//    No LDS gate exchange (round-4's 8.7M bank conflicts came from it).
// DIMS: DAYS=30 TOPICS=20 T=128 E=300 H=256 DH=64; text batch = 600.

typedef __attribute__((ext_vector_type(8))) short short8;
typedef __attribute__((ext_vector_type(8))) __bf16 bf16x8;
typedef __attribute__((ext_vector_type(4))) float f4;

static __device__ __forceinline__ short f2bf(float f){
  unsigned u = __builtin_bit_cast(unsigned, f);
  u = u + 0x7fffu + ((u >> 16) & 1u);
  return (short)(u >> 16);
}
static __device__ __forceinline__ float b2f(short s){
  unsigned u = ((unsigned)(unsigned short)s) << 16;
  return __builtin_bit_cast(float, u);
}
static __device__ __forceinline__ float sigm(float x){ return 1.f/(1.f + __expf(-x)); }
static __device__ __forceinline__ float tanh_f(float x){
  float e = __expf(-2.f*fabsf(x));
  float t = (1.f - e)/(1.f + e);
  return x < 0.f ? -t : t;
}
static __device__ __forceinline__ f4 mfma16(short8 a, short8 b, f4 c){
  return __builtin_amdgcn_mfma_f32_16x16x32_bf16(
      __builtin_bit_cast(bf16x8, a), __builtin_bit_cast(bf16x8, b), c, 0, 0, 0);
}

// ---------------- fp32 [N,K] -> bf16 flat [N,Kp] (day path) --------------
__global__ void k_cvt_pad(const float* __restrict__ in, short* __restrict__ out,
                          int N, int K, int Kp){
  long total = (long)N * Kp;
  for (long i = (long)blockIdx.x*blockDim.x + threadIdx.x; i < total;
       i += (long)gridDim.x*blockDim.x){
    int k = (int)(i % Kp); long n = i / Kp;
    float v = (k < K) ? in[n*K + k] : 0.f;
    out[i] = f2bf(v);
  }
}

// ---- fp32 [N,K] -> bf16 W4 fragment layout: frag(nt,kt,l,e) = W[nt*16+(l&15)][kt*32+(l>>4)*8+e]
__global__ void k_cvt_repack(const float* __restrict__ in, short* __restrict__ out,
                             int N, int K, int KT){
  long total = (long)(N/16) * KT * 64;
  for (long idx = (long)blockIdx.x*blockDim.x + threadIdx.x; idx < total;
       idx += (long)gridDim.x*blockDim.x){
    int l  = (int)(idx & 63);
    long f = idx >> 6;
    int kt = (int)(f % KT);
    int nt = (int)(f / KT);
    int row = nt*16 + (l & 15);
    int kb  = kt*32 + (l >> 4)*8;
    #pragma unroll
    for (int e = 0; e < 8; ++e){
      int k = kb + e;
      float v = (k < K) ? in[(long)row*K + k] : 0.f;
      out[idx*8 + e] = f2bf(v);
    }
  }
}

// ---------------- big GEMM: C[perm(m)][1024] = A[m,K] @ W4^T + bias -------
// 64-row blocks compute all 1024 cols: A read ONCE, staged LDS->regs.
// perm(m) = (m % TT)*SS + m/TT   (TT=1 -> identity).
template<bool A_F32, int KT>
__global__ __launch_bounds__(256, 2) void k_gemm_big(
    const void* __restrict__ Av, const short* __restrict__ W4,
    const float* __restrict__ bias, short* __restrict__ Cout,
    int M, int Ka, int TT, int SS)
{
  constexpr int Kp = KT*32;
  __shared__ short Afr[4*KT*64*8];     // A fragments (<=40 KB)
  __shared__ short Cst[64*128];        // C stage (16 KB)
  int tid = threadIdx.x;
  int w = tid >> 6, l = tid & 63, lr = l & 15, lg = l >> 4;
  int m0 = blockIdx.x*64;
  const float* Af = (const float*)Av;
  const short* Ab = (const short*)Av;

  for (int i2 = tid; i2 < 64*(Kp/8); i2 += 256){
    int row = i2 / (Kp/8);
    int kb  = (i2 % (Kp/8))*8;
    int mt = row >> 4, kt = kb >> 5, ls = (row & 15) + 16*((kb & 31) >> 3);
    short8 v = {0,0,0,0,0,0,0,0};
    int grow = m0 + row;
    if (grow < M){
      if (A_F32){
        #pragma unroll
        for (int e = 0; e < 8; ++e){
          int k = kb + e;
          v[e] = (k < Ka) ? f2bf(Af[(long)grow*Ka + k]) : (short)0;
        }
      } else {
        v = *(const short8*)(Ab + (long)grow*Kp + kb);
      }
    }
    *(short8*)&Afr[(((mt*KT) + kt)*64 + ls)*8] = v;
  }
  __syncthreads();

  short8 areg[4][KT];
  #pragma unroll
  for (int mt = 0; mt < 4; ++mt)
    #pragma unroll
    for (int kt = 0; kt < KT; ++kt)
      areg[mt][kt] = *(const short8*)&Afr[(((mt*KT) + kt)*64 + l)*8];

  for (int nc = 0; nc < 8; ++nc){
    f4 acc[4][2];
    #pragma unroll
    for (int mt = 0; mt < 4; ++mt){ acc[mt][0]=(f4){0,0,0,0}; acc[mt][1]=(f4){0,0,0,0}; }
    #pragma unroll
    for (int kt = 0; kt < KT; ++kt){
      short8 b0 = *(const short8*)&W4[(((long)(nc*8 + w*2 + 0)*KT + kt)*64 + l)*8];
      short8 b1 = *(const short8*)&W4[(((long)(nc*8 + w*2 + 1)*KT + kt)*64 + l)*8];
      #pragma unroll
      for (int mt = 0; mt < 4; ++mt){
        acc[mt][0] = mfma16(areg[mt][kt], b0, acc[mt][0]);
        acc[mt][1] = mfma16(areg[mt][kt], b1, acc[mt][1]);
      }
    }
    __syncthreads();
    #pragma unroll
    for (int jj = 0; jj < 2; ++jj){
      int cl = w*32 + jj*16 + lr;
      float bv = bias ? bias[nc*128 + cl] : 0.f;
      #pragma unroll
      for (int mt = 0; mt < 4; ++mt){
        #pragma unroll
        for (int r = 0; r < 4; ++r)
          Cst[(mt*16 + lg*4 + r)*128 + cl] = f2bf(acc[mt][jj][r] + bv);
      }
    }
    __syncthreads();
    #pragma unroll
    for (int it = 0; it < 4; ++it){
      int row = it*16 + (tid >> 4);
      int grow = m0 + row;
      if (grow < M){
        long prow = (long)(grow % TT)*SS + grow/TT;
        *(short8*)(Cout + prow*1024 + nc*128 + (tid & 15)*8) =
            *(const short8*)&Cst[row*128 + (tid & 15)*8];
      }
    }
  }
}

// ---------------- persistent LSTM layer (register-gate version) -----------
// G: [T][NS][1024] bf16 (inproj+bias).  W4h: Whh fragment layout (KT=8).
// Wave w's B-tiles: nt = g*16 + w*2 + ut  (g=gate 0..3, ut=0..1).
// Lane owns (s = mt*16+lg*4+r, u = (w*2+ut)*16+lr): all 4 gates in-register.
__global__ __launch_bounds__(512, 1) void k_lstm_seq(
    const short* __restrict__ G, const short* __restrict__ W4h,
    short* __restrict__ y_bf,    // opt [T][NS][256]
    float* __restrict__ y_f32,   // opt [T][NS][256]
    short* __restrict__ hfin_bf, // opt [NS][256]
    float* __restrict__ hfin_f32,// opt [NS][256]
    int NS, int T)
{
  __shared__ short hfrag[2*8*64*8];   // 16 KB: h in A-fragment layout
  int tid = threadIdx.x;
  int w = tid >> 6, l = tid & 63, lr = l & 15, lg = l >> 4;
  int s0 = blockIdx.x * 32;

  for (int i = tid; i < 2*8*64*8; i += 512) hfrag[i] = 0;
  float c[16];
  #pragma unroll
  for (int i = 0; i < 16; ++i) c[i] = 0.f;
  __syncthreads();

  for (int t = 0; t < T; ++t){
    // --- A fragments (all of h) to registers ---
    short8 areg[2][8];
    #pragma unroll
    for (int kt = 0; kt < 8; ++kt){
      areg[0][kt] = *(const short8*)&hfrag[((0*8 + kt)*64 + l)*8];
      areg[1][kt] = *(const short8*)&hfrag[((1*8 + kt)*64 + l)*8];
    }
    // --- W stream + MFMA: acc[mt][j], j = g*2+ut ---
    f4 acc[2][8];
    #pragma unroll
    for (int j = 0; j < 8; ++j){ acc[0][j]=(f4){0,0,0,0}; acc[1][j]=(f4){0,0,0,0}; }
    #pragma unroll
    for (int j = 0; j < 8; ++j){
      int g = j >> 1, ut = j & 1;
      int nt = g*16 + w*2 + ut;
      #pragma unroll
      for (int kt = 0; kt < 8; ++kt){
        short8 b = *(const short8*)&W4h[(((long)nt*8 + kt)*64 + l)*8];
        acc[0][j] = mfma16(areg[0][kt], b, acc[0][j]);
        acc[1][j] = mfma16(areg[1][kt], b, acc[1][j]);
      }
    }
    // --- G inproj loads (issued after MFMA block: in-order vmcnt won't
    //     make MFMA waits depend on these HBM loads) ---
    short gq[8][8];
    #pragma unroll
    for (int j = 0; j < 8; ++j){
      int g = j >> 1, ut = j & 1;
      int ucol = (g << 8) + ((w*2 + ut) << 4) + lr;
      #pragma unroll
      for (int mt = 0; mt < 2; ++mt){
        #pragma unroll
        for (int r = 0; r < 4; ++r){
          int s = mt*16 + lg*4 + r;
          gq[j][mt*4+r] = (s0 + s < NS)
              ? G[((long)t*NS + s0 + s)*1024 + ucol] : (short)0;
        }
      }
    }
    __syncthreads();   // all hfrag reads done; safe to overwrite
    // --- register-only cell update ---
    #pragma unroll
    for (int mt = 0; mt < 2; ++mt){
      #pragma unroll
      for (int ut = 0; ut < 2; ++ut){
        #pragma unroll
        for (int r = 0; r < 4; ++r){
          int s = mt*16 + lg*4 + r;
          bool ok = (s0 + s < NS);
          float gi = acc[mt][0+ut][r] + b2f(gq[0+ut][mt*4+r]);
          float gf = acc[mt][2+ut][r] + b2f(gq[2+ut][mt*4+r]);
          float gg = acc[mt][4+ut][r] + b2f(gq[4+ut][mt*4+r]);
          float go = acc[mt][6+ut][r] + b2f(gq[6+ut][mt*4+r]);
          int ci = (mt*2 + ut)*4 + r;
          float cn = sigm(gf)*c[ci] + sigm(gi)*tanh_f(gg);
          float hn = sigm(go)*tanh_f(cn);
          c[ci] = cn;
          if (ok){
            short hb = f2bf(hn);
            int u = ((w*2 + ut) << 4) + lr;
            int ls = (s & 15) + 16*(ut*2 + (lr >> 3));
            hfrag[((mt*8 + w)*64 + ls)*8 + (lr & 7)] = hb;
            long grow = (long)t*NS + s0 + s;
            if (y_bf)  y_bf[grow*256 + u]  = hb;
            if (y_f32) y_f32[grow*256 + u] = hn;
            if (t == T-1){
              if (hfin_bf)  hfin_bf[(long)(s0+s)*256 + u]  = hb;
              if (hfin_f32) hfin_f32[(long)(s0+s)*256 + u] = hn;
            }
          }
        }
      }
    }
    __syncthreads();   // h writes visible to next step's reads
  }
}

// ---------------- small flat GEMM (day path): C[M,N]=A@Bt^T+bias ---------
template<bool A_F32>
__global__ __launch_bounds__(256) void k_gemm_flat(
    const void* __restrict__ Av, const short* __restrict__ Bt,
    const float* __restrict__ bias, short* __restrict__ C,
    int M, int N, int Kp, int Ka)
{
  int w = threadIdx.x >> 6, l = threadIdx.x & 63;
  int m0 = blockIdx.x*128 + w*32;
  int n0 = blockIdx.y*128;
  int lr = l & 15, lg = l >> 4;
  f4 acc[2][8];
  #pragma unroll
  for (int i=0;i<2;++i)
    #pragma unroll
    for (int j=0;j<8;++j) acc[i][j] = (f4){0.f,0.f,0.f,0.f};
  const short* Ab = (const short*)Av;
  int nkt = Kp >> 5;
  for (int kt = 0; kt < nkt; ++kt){
    int kb = kt*32 + lg*8;
    short8 a[2];
    #pragma unroll
    for (int mt = 0; mt < 2; ++mt){
      int m = m0 + mt*16 + lr;
      short8 av = {0,0,0,0,0,0,0,0};
      if (m < M) av = *(const short8*)(Ab + (long)m*Kp + kb);
      a[mt] = av;
    }
    #pragma unroll
    for (int nt = 0; nt < 8; ++nt){
      short8 b = *(const short8*)(Bt + (long)(n0 + nt*16 + lr)*Kp + kb);
      acc[0][nt] = mfma16(a[0], b, acc[0][nt]);
      acc[1][nt] = mfma16(a[1], b, acc[1][nt]);
    }
  }
  #pragma unroll
  for (int nt = 0; nt < 8; ++nt){
    int col = n0 + nt*16 + lr;
    float bv = bias ? bias[col] : 0.f;
    #pragma unroll
    for (int mt = 0; mt < 2; ++mt){
      #pragma unroll
      for (int r = 0; r < 4; ++r){
        int row = m0 + mt*16 + lg*4 + r;
        if (row < M) C[(long)row*N + col] = f2bf(acc[mt][nt][r] + bv);
      }
    }
  }
}

// ---------------- day LSTM (batch=1, hidden 64, gates 256), 1 block ------
__global__ __launch_bounds__(1024) void k_day_lstm(
    const short* __restrict__ Gd,   // [T,256] bf16 (inproj+bias)
    const float* __restrict__ Whh,  // [256,64] fp32
    short* __restrict__ y_bf,       // opt [T,64]
    float* __restrict__ y_f32,      // opt [T,64]
    float* __restrict__ hT_f32,     // opt [64]
    int T)
{
  __shared__ float whhT[64*257];
  __shared__ float h[64], cc[64], part[4][256], gates[256];
  int tid = threadIdx.x;
  for (int i = tid; i < 256*64; i += 1024){
    int n = i >> 6, k = i & 63;
    whhT[k*257 + n] = Whh[i];
  }
  if (tid < 64){ h[tid]=0.f; cc[tid]=0.f; }
  __syncthreads();
  int n = tid & 255, kg = tid >> 8;
  for (int t = 0; t < T; ++t){
    float p = 0.f;
    #pragma unroll
    for (int kk = 0; kk < 16; ++kk){
      int k = kg*16 + kk;
      p += h[k]*whhT[k*257+n];
    }
    part[kg][n] = p;
    __syncthreads();
    if (tid < 256)
      gates[tid] = b2f(Gd[t*256+tid]) + part[0][tid]+part[1][tid]+part[2][tid]+part[3][tid];
    __syncthreads();
    if (tid < 64){
      float gi=gates[tid], gf=gates[64+tid], gg=gates[128+tid], go=gates[192+tid];
      float cn = sigm(gf)*cc[tid] + sigm(gi)*tanh_f(gg);
      float hn = sigm(go)*tanh_f(cn);
      cc[tid]=cn; h[tid]=hn;
      if (y_bf)  y_bf[t*64+tid]  = f2bf(hn);
      if (y_f32) y_f32[t*64+tid] = hn;
      if (hT_f32 && t==T-1) hT_f32[tid] = hn;
    }
    __syncthreads();
  }
}

// ---------------- per-day topic attention (truncated top-p 0.8) ----------
// y1 layout [t][30][256] f32.
__global__ __launch_bounds__(256) void k_topic_attn(
    const float* __restrict__ y1, const float* __restrict__ hT,
    const float* __restrict__ w1W, const float* __restrict__ w1b,
    short* __restrict__ dayh)
{
  int d = blockIdx.x, tid = threadIdx.x;
  __shared__ float hf[256], red[4], sc[20], wk[20], c0s;
  hf[tid] = hT[d*256+tid];
  __syncthreads();
  float v = 0.f;
  for (int j=0;j<256;++j) v += hf[j]*w1W[j*256+tid];
  float p0 = w1b[tid]*hf[tid];
  #pragma unroll
  for (int o=32;o>0;o>>=1) p0 += __shfl_down(p0,o);
  if ((tid&63)==0) red[tid>>6] = p0;
  __syncthreads();
  if (tid==0) c0s = red[0]+red[1]+red[2]+red[3];
  __syncthreads();
  for (int t=0;t<20;++t){
    float p = y1[(t*30 + d)*256 + tid]*v;
    #pragma unroll
    for (int o=32;o>0;o>>=1) p += __shfl_down(p,o);
    if ((tid&63)==0) red[tid>>6] = p;
    __syncthreads();
    if (tid==0) sc[t] = red[0]+red[1]+red[2]+red[3] + c0s;
    __syncthreads();
  }
  if (tid==0){
    float mx = -1e30f;
    for (int t=0;t<20;++t) mx = fmaxf(mx, sc[t]);
    float ss = 0.f;
    for (int t=0;t<20;++t){ sc[t] = __expf(sc[t]-mx); ss += sc[t]; }
    float inv = 1.f/ss;
    for (int t=0;t<20;++t) sc[t] *= inv;
    for (int t=0;t<20;++t){
      float pref = 0.f;
      for (int q=0;q<20;++q)
        if (sc[q]>sc[t] || (sc[q]==sc[t] && q<t)) pref += sc[q];
      wk[t] = (pref <= 0.8f) ? sc[t] : 0.f;
    }
  }
  __syncthreads();
  float a = 0.f;
  for (int t=0;t<20;++t) a += wk[t]*y1[(t*30 + d)*256 + tid];
  dayh[d*256+tid] = f2bf(a);
}

// ---------------- final: day attention + linears + head ------------------
__global__ __launch_bounds__(64) void k_final(
    const float* __restrict__ y1,  const float* __restrict__ hT,
    const float* __restrict__ w2W, const float* __restrict__ w2b,
    const float* __restrict__ l1W, const float* __restrict__ l1b,
    const float* __restrict__ l2W, const float* __restrict__ l2b,
    const float* __restrict__ hW,  const float* __restrict__ hb,
    const float* __restrict__ prev, float* __restrict__ out)
{
  int tid = threadIdx.x;
  __shared__ float hf[64], v2[64], sc[30], ctx[64], h1[48], h2[16], c0s;
  hf[tid] = hT[tid];
  __syncthreads();
  { float v=0.f; for (int j=0;j<64;++j) v += hf[j]*w2W[j*64+tid]; v2[tid]=v; }
  if (tid==0){ float c0=0.f; for (int j=0;j<64;++j) c0 += w2b[j]*hf[j]; c0s=c0; }
  __syncthreads();
  if (tid<30){ float sacc=c0s; for (int k=0;k<64;++k) sacc += y1[tid*64+k]*v2[k]; sc[tid]=sacc; }
  __syncthreads();
  if (tid==0){
    float mx=-1e30f; for (int d=0;d<30;++d) mx=fmaxf(mx,sc[d]);
    float ss=0.f; for (int d=0;d<30;++d){ sc[d]=__expf(sc[d]-mx); ss+=sc[d]; }
    float inv=1.f/ss; for (int d=0;d<30;++d) sc[d]*=inv;
  }
  __syncthreads();
  { float cx=0.f; for (int d=0;d<30;++d) cx += sc[d]*y1[d*64+tid]; ctx[tid]=cx; }
  __syncthreads();
  if (tid<48){ float sacc=l1b[tid]; for (int k=0;k<64;++k) sacc += ctx[k]*l1W[tid*64+k]; h1[tid]=sacc; }
  __syncthreads();
  if (tid<16){ float sacc=l2b[tid]; for (int k=0;k<48;++k) sacc += h1[k]*l2W[tid*48+k]; h2[tid]=sacc; }
  __syncthreads();
  if (tid<4){
    float sacc = hb[tid];
    for (int cI=0;cI<16;++cI) sacc += h2[cI]*hW[tid*20+cI];
    for (int cI=0;cI<4; ++cI) sacc += prev[tid*4+cI]*hW[tid*20+16+cI];
    out[tid] = sacc;
  }
}

// ========================================================================
extern "C" void kernel_launch(void* const* d_in, const int* in_sizes, int n_in,
                              void* d_out, int out_size, void* d_ws, size_t ws_size,
                              hipStream_t stream)
{
  const float* X        = (const float*)d_in[0];   // [30,20,128,300]
  const float* prev     = (const float*)d_in[1];
  const float* tWih0    = (const float*)d_in[2];   // [1024,300]
  const float* tWhh0    = (const float*)d_in[3];   // [1024,256]
  const float* tb0      = (const float*)d_in[4];
  // d_in[5..7] text layer-1: DEAD
  const float* pWih0    = (const float*)d_in[8];
  const float* pWhh0    = (const float*)d_in[9];
  const float* pb0      = (const float*)d_in[10];
  const float* pWih1    = (const float*)d_in[11];
  const float* pWhh1    = (const float*)d_in[12];
  const float* pb1      = (const float*)d_in[13];
  const float* dWih0    = (const float*)d_in[14];
  const float* dWhh0    = (const float*)d_in[15];
  const float* db0      = (const float*)d_in[16];
  const float* dWih1    = (const float*)d_in[17];
  const float* dWhh1    = (const float*)d_in[18];
  const float* db1      = (const float*)d_in[19];
  const float* w1W      = (const float*)d_in[20];
  const float* w1b      = (const float*)d_in[21];
  const float* w2W      = (const float*)d_in[22];
  const float* w2b      = (const float*)d_in[23];
  const float* l1W      = (const float*)d_in[24];
  const float* l1b      = (const float*)d_in[25];
  const float* l2W      = (const float*)d_in[26];
  const float* l2b      = (const float*)d_in[27];
  const float* hW       = (const float*)d_in[28];
  const float* hb       = (const float*)d_in[29];
  float* out = (float*)d_out;

  char* wsb = (char*)d_ws;
  size_t off = 0;
  auto alloc = [&](size_t bytes)->void*{
    void* p = wsb + off;
    off = (off + bytes + 255) & ~(size_t)255;
    return p;
  };
  short* G0      = (short*)alloc((size_t)128*600*1024*2);  // [t][seq][1024]
  short* W4tWih  = (short*)alloc((size_t)1024*320*2);
  short* W4tWhh  = (short*)alloc((size_t)1024*256*2);
  short* W4p0i   = (short*)alloc((size_t)1024*256*2);
  short* W4p0h   = (short*)alloc((size_t)1024*256*2);
  short* W4p1i   = (short*)alloc((size_t)1024*256*2);
  short* W4p1h   = (short*)alloc((size_t)1024*256*2);
  short* dW0i    = (short*)alloc((size_t)256*256*2);
  short* dW1i    = (short*)alloc((size_t)256*64*2);
  short* h_text  = (short*)alloc((size_t)600*256*2);       // [seq][256]
  short* Gt0     = (short*)alloc((size_t)20*30*1024*2);    // [t][d][1024]
  short* y_t0    = (short*)alloc((size_t)20*30*256*2);     // [t][d][256]
  float* h_topf  = (float*)alloc((size_t)30*256*4);
  short* Gt1     = (short*)alloc((size_t)20*30*1024*2);
  float* y_t1f   = (float*)alloc((size_t)20*30*256*4);
  short* dayh    = (short*)alloc((size_t)30*256*2);
  short* Gd0     = (short*)alloc((size_t)30*256*2);
  short* y_d0    = (short*)alloc((size_t)30*64*2);
  float* h_d0f   = (float*)alloc((size_t)64*4);
  short* Gd1     = (short*)alloc((size_t)30*256*2);
  float* y_d1f   = (float*)alloc((size_t)30*64*4);
  (void)ws_size; (void)in_sizes; (void)n_in; (void)out_size;

  // --- weight conversions ---
  k_cvt_repack<<<256,256,0,stream>>>(tWih0, W4tWih, 1024, 300, 10);
  k_cvt_repack<<<256,256,0,stream>>>(tWhh0, W4tWhh, 1024, 256, 8);
  k_cvt_repack<<<256,256,0,stream>>>(pWih0, W4p0i, 1024, 256, 8);
  k_cvt_repack<<<256,256,0,stream>>>(pWhh0, W4p0h, 1024, 256, 8);
  k_cvt_repack<<<256,256,0,stream>>>(pWih1, W4p1i, 1024, 256, 8);
  k_cvt_repack<<<256,256,0,stream>>>(pWhh1, W4p1h, 1024, 256, 8);
  k_cvt_pad<<<256,256,0,stream>>>(dWih0, dW0i, 256, 256, 256);
  k_cvt_pad<<<64,256,0,stream>>>(dWih1, dW1i, 256, 64, 64);

  // --- text L0 input projection: rows s*128+t -> G0[t][s] ---
  k_gemm_big<true,10><<<1200,256,0,stream>>>((const void*)X, W4tWih, tb0, G0,
                                             76800, 300, 128, 600);
  // --- text L0 recurrence: ONE dispatch, 19 blocks x 32 seqs ---
  k_lstm_seq<<<19,512,0,stream>>>(G0, W4tWhh, nullptr, nullptr,
                                  h_text, nullptr, 600, 128);
  // --- topic L0: inproj (rows d*20+t -> Gt0[t][d]) + recurrence ---
  k_gemm_big<false,8><<<10,256,0,stream>>>((const void*)h_text, W4p0i, pb0, Gt0,
                                           600, 256, 20, 30);
  k_lstm_seq<<<1,512,0,stream>>>(Gt0, W4p0h, y_t0, nullptr,
                                 nullptr, h_topf, 30, 20);
  // --- topic L1: inproj (rows t*30+d identity) + recurrence ---
  k_gemm_big<false,8><<<10,256,0,stream>>>((const void*)y_t0, W4p1i, pb1, Gt1,
                                           600, 256, 1, 600);
  k_lstm_seq<<<1,512,0,stream>>>(Gt1, W4p1h, nullptr, y_t1f,
                                 nullptr, nullptr, 30, 20);
  // --- per-day topic attention ---
  k_topic_attn<<<30,256,0,stream>>>(y_t1f, h_topf, w1W, w1b, dayh);
  // --- day LSTM (batch=1) ---
  k_gemm_flat<false><<<dim3(1,2),256,0,stream>>>((const void*)dayh, dW0i, db0, Gd0,
                                                 30, 256, 256, 256);
  k_day_lstm<<<1,1024,0,stream>>>(Gd0, dWhh0, y_d0, nullptr, h_d0f, 30);
  k_gemm_flat<false><<<dim3(1,2),256,0,stream>>>((const void*)y_d0, dW1i, db1, Gd1,
                                                 30, 256, 64, 64);
  k_day_lstm<<<1,1024,0,stream>>>(Gd1, dWhh1, nullptr, y_d1f, nullptr, 30);
  // --- final ---
  k_final<<<1,64,0,stream>>>(y_d1f, h_d0f, w2W, w2b, l1W, l1b, l2W, l2b,
                             hW, hb, prev, out);
}

// Round 6
// 3513.074 us; speedup vs baseline: 1.7031x; 1.7031x over previous
//
#include <hip/hip_runtime.h>
#include <hip/hip_bf16.h>

// Model_26439818674684: hierarchical LSTM forecaster.
//  - text LSTM layer 1 is DEAD (reference uses layer-0 final hidden only).
//  - input projections hoisted into bf16 MFMA GEMMs (bias folded), gate
//    buffers in [t][seq][1024] layout.
//  - recurrence kernel (round 6): register-gate MFMA (round-5 math, absmax
//    0.0) + G double-buffered through padded LDS (T14 issue-early/write-late
//    split) + software-pipelined W stream (bb[2][8] lookahead). Removes the
//    round-5 serialization (64 scalar HBM loads batched at 128 VGPRs).
// DIMS: DAYS=30 TOPICS=20 T=128 E=300 H=256 DH=64; text batch = 600.

typedef __attribute__((ext_vector_type(8))) short short8;
typedef __attribute__((ext_vector_type(8))) __bf16 bf16x8;
typedef __attribute__((ext_vector_type(4))) float f4;

static __device__ __forceinline__ short f2bf(float f){
  unsigned u = __builtin_bit_cast(unsigned, f);
  u = u + 0x7fffu + ((u >> 16) & 1u);
  return (short)(u >> 16);
}
static __device__ __forceinline__ float b2f(short s){
  unsigned u = ((unsigned)(unsigned short)s) << 16;
  return __builtin_bit_cast(float, u);
}
static __device__ __forceinline__ float sigm(float x){ return 1.f/(1.f + __expf(-x)); }
static __device__ __forceinline__ float tanh_f(float x){
  float e = __expf(-2.f*fabsf(x));
  float t = (1.f - e)/(1.f + e);
  return x < 0.f ? -t : t;
}
static __device__ __forceinline__ f4 mfma16(short8 a, short8 b, f4 c){
  return __builtin_amdgcn_mfma_f32_16x16x32_bf16(
      __builtin_bit_cast(bf16x8, a), __builtin_bit_cast(bf16x8, b), c, 0, 0, 0);
}

// ---------------- fp32 [N,K] -> bf16 flat [N,Kp] (day path) --------------
__global__ void k_cvt_pad(const float* __restrict__ in, short* __restrict__ out,
                          int N, int K, int Kp){
  long total = (long)N * Kp;
  for (long i = (long)blockIdx.x*blockDim.x + threadIdx.x; i < total;
       i += (long)gridDim.x*blockDim.x){
    int k = (int)(i % Kp); long n = i / Kp;
    float v = (k < K) ? in[n*K + k] : 0.f;
    out[i] = f2bf(v);
  }
}

// ---- fp32 [N,K] -> bf16 W4 fragment layout: frag(nt,kt,l,e) = W[nt*16+(l&15)][kt*32+(l>>4)*8+e]
__global__ void k_cvt_repack(const float* __restrict__ in, short* __restrict__ out,
                             int N, int K, int KT){
  long total = (long)(N/16) * KT * 64;
  for (long idx = (long)blockIdx.x*blockDim.x + threadIdx.x; idx < total;
       idx += (long)gridDim.x*blockDim.x){
    int l  = (int)(idx & 63);
    long f = idx >> 6;
    int kt = (int)(f % KT);
    int nt = (int)(f / KT);
    int row = nt*16 + (l & 15);
    int kb  = kt*32 + (l >> 4)*8;
    #pragma unroll
    for (int e = 0; e < 8; ++e){
      int k = kb + e;
      float v = (k < K) ? in[(long)row*K + k] : 0.f;
      out[idx*8 + e] = f2bf(v);
    }
  }
}

// ---------------- big GEMM: C[perm(m)][1024] = A[m,K] @ W4^T + bias -------
template<bool A_F32, int KT>
__global__ __launch_bounds__(256, 2) void k_gemm_big(
    const void* __restrict__ Av, const short* __restrict__ W4,
    const float* __restrict__ bias, short* __restrict__ Cout,
    int M, int Ka, int TT, int SS)
{
  constexpr int Kp = KT*32;
  __shared__ short Afr[4*KT*64*8];     // A fragments (<=40 KB)
  __shared__ short Cst[64*128];        // C stage (16 KB)
  int tid = threadIdx.x;
  int w = tid >> 6, l = tid & 63, lr = l & 15, lg = l >> 4;
  int m0 = blockIdx.x*64;
  const float* Af = (const float*)Av;
  const short* Ab = (const short*)Av;

  for (int i2 = tid; i2 < 64*(Kp/8); i2 += 256){
    int row = i2 / (Kp/8);
    int kb  = (i2 % (Kp/8))*8;
    int mt = row >> 4, kt = kb >> 5, ls = (row & 15) + 16*((kb & 31) >> 3);
    short8 v = {0,0,0,0,0,0,0,0};
    int grow = m0 + row;
    if (grow < M){
      if (A_F32){
        #pragma unroll
        for (int e = 0; e < 8; ++e){
          int k = kb + e;
          v[e] = (k < Ka) ? f2bf(Af[(long)grow*Ka + k]) : (short)0;
        }
      } else {
        v = *(const short8*)(Ab + (long)grow*Kp + kb);
      }
    }
    *(short8*)&Afr[(((mt*KT) + kt)*64 + ls)*8] = v;
  }
  __syncthreads();

  short8 areg[4][KT];
  #pragma unroll
  for (int mt = 0; mt < 4; ++mt)
    #pragma unroll
    for (int kt = 0; kt < KT; ++kt)
      areg[mt][kt] = *(const short8*)&Afr[(((mt*KT) + kt)*64 + l)*8];

  for (int nc = 0; nc < 8; ++nc){
    f4 acc[4][2];
    #pragma unroll
    for (int mt = 0; mt < 4; ++mt){ acc[mt][0]=(f4){0,0,0,0}; acc[mt][1]=(f4){0,0,0,0}; }
    #pragma unroll
    for (int kt = 0; kt < KT; ++kt){
      short8 b0 = *(const short8*)&W4[(((long)(nc*8 + w*2 + 0)*KT + kt)*64 + l)*8];
      short8 b1 = *(const short8*)&W4[(((long)(nc*8 + w*2 + 1)*KT + kt)*64 + l)*8];
      #pragma unroll
      for (int mt = 0; mt < 4; ++mt){
        acc[mt][0] = mfma16(areg[mt][kt], b0, acc[mt][0]);
        acc[mt][1] = mfma16(areg[mt][kt], b1, acc[mt][1]);
      }
    }
    __syncthreads();
    #pragma unroll
    for (int jj = 0; jj < 2; ++jj){
      int cl = w*32 + jj*16 + lr;
      float bv = bias ? bias[nc*128 + cl] : 0.f;
      #pragma unroll
      for (int mt = 0; mt < 4; ++mt){
        #pragma unroll
        for (int r = 0; r < 4; ++r)
          Cst[(mt*16 + lg*4 + r)*128 + cl] = f2bf(acc[mt][jj][r] + bv);
      }
    }
    __syncthreads();
    #pragma unroll
    for (int it = 0; it < 4; ++it){
      int row = it*16 + (tid >> 4);
      int grow = m0 + row;
      if (grow < M){
        long prow = (long)(grow % TT)*SS + grow/TT;
        *(short8*)(Cout + prow*1024 + nc*128 + (tid & 15)*8) =
            *(const short8*)&Cst[row*128 + (tid & 15)*8];
      }
    }
  }
}

// ---------------- persistent LSTM layer (register-gate + LDS-G) -----------
// G: [T][NS][1024] bf16 (inproj+bias).  W4h: Whh fragment layout (KT=8).
// Wave w's B-tiles: nt = g*16 + w*2 + ut.  Lane owns (s = mt*16+lg*4+r,
// u = (w*2+ut)*16+lr): all 4 gates in-register after MFMA.
// G double-buffered in LDS (row stride 1036 -> conflict-free scalar reads);
// staged reg->LDS with issue-early / write-late split (T14).
#define GSTRIDE 1036
__global__ __launch_bounds__(512, 2) void k_lstm_seq(
    const short* __restrict__ G, const short* __restrict__ W4h,
    short* __restrict__ y_bf,    // opt [T][NS][256]
    float* __restrict__ y_f32,   // opt [T][NS][256]
    short* __restrict__ hfin_bf, // opt [NS][256]
    float* __restrict__ hfin_f32,// opt [NS][256]
    int NS, int T)
{
  __shared__ short hfrag[2*8*64*8];        // 16 KB: h in A-fragment layout
  __shared__ short gbuf[2][32*GSTRIDE];    // ~130 KB: G double buffer
  int tid = threadIdx.x;
  int w = tid >> 6, l = tid & 63, lr = l & 15, lg = l >> 4;
  int s0 = blockIdx.x * 32;
  int sr = tid >> 4;            // staging row (0..31)
  int sc = (tid & 15) * 8;      // staging col base

  for (int i = tid; i < 2*8*64*8; i += 512) hfrag[i] = 0;
  float c[16];
  #pragma unroll
  for (int i = 0; i < 16; ++i) c[i] = 0.f;

  // --- prologue: stage G(0) ---
  {
    const short* src = G + ((long)0*NS + s0 + sr)*1024 + sc;
    short8 gst[8];
    #pragma unroll
    for (int k = 0; k < 8; ++k) gst[k] = *(const short8*)(src + k*128);
    #pragma unroll
    for (int k = 0; k < 8; ++k)
      *(short8*)&gbuf[0][sr*GSTRIDE + sc + k*128] = gst[k];
  }
  __syncthreads();

  for (int t = 0; t < T; ++t){
    // --- issue next-step G loads EARLY (latency hides under W-MFMA) ---
    int tl = (t+1 < T) ? t+1 : t;
    const short* src = G + ((long)tl*NS + s0 + sr)*1024 + sc;
    short8 gst[8];
    #pragma unroll
    for (int k = 0; k < 8; ++k) gst[k] = *(const short8*)(src + k*128);

    // --- A fragments (all of h) to registers ---
    short8 areg[2][8];
    #pragma unroll
    for (int kt = 0; kt < 8; ++kt){
      areg[0][kt] = *(const short8*)&hfrag[((0*8 + kt)*64 + l)*8];
      areg[1][kt] = *(const short8*)&hfrag[((1*8 + kt)*64 + l)*8];
    }

    // --- W stream + MFMA, software-pipelined over j (2-deep) ---
    f4 acc[2][8];
    #pragma unroll
    for (int j = 0; j < 8; ++j){ acc[0][j]=(f4){0,0,0,0}; acc[1][j]=(f4){0,0,0,0}; }
    short8 bb[2][8];
    {
      int nt0 = 0*16 + w*2 + 0;   // j=0: g=0,ut=0
      #pragma unroll
      for (int kt = 0; kt < 8; ++kt)
        bb[0][kt] = *(const short8*)&W4h[(((long)nt0*8 + kt)*64 + l)*8];
    }
    #pragma unroll
    for (int j = 0; j < 8; ++j){
      if (j < 7){
        int jn = j + 1;
        int nt = (jn >> 1)*16 + w*2 + (jn & 1);
        #pragma unroll
        for (int kt = 0; kt < 8; ++kt)
          bb[(j+1)&1][kt] = *(const short8*)&W4h[(((long)nt*8 + kt)*64 + l)*8];
      }
      #pragma unroll
      for (int kt = 0; kt < 8; ++kt){
        acc[0][j] = mfma16(areg[0][kt], bb[j&1][kt], acc[0][j]);
        acc[1][j] = mfma16(areg[1][kt], bb[j&1][kt], acc[1][j]);
      }
    }
    __syncthreads();   // all hfrag reads done; safe to overwrite

    // --- register cell update; gates inproj from LDS (conflict-free) ---
    const short* Gl = gbuf[t&1];
    #pragma unroll
    for (int mt = 0; mt < 2; ++mt){
      #pragma unroll
      for (int ut = 0; ut < 2; ++ut){
        #pragma unroll
        for (int r = 0; r < 4; ++r){
          int s = mt*16 + lg*4 + r;
          if (s0 + s < NS){
            int u = ((w*2 + ut) << 4) + lr;
            int gbase = s*GSTRIDE + u;
            float gi = acc[mt][0+ut][r] + b2f(Gl[gbase]);
            float gf = acc[mt][2+ut][r] + b2f(Gl[gbase + 256]);
            float gg = acc[mt][4+ut][r] + b2f(Gl[gbase + 512]);
            float go = acc[mt][6+ut][r] + b2f(Gl[gbase + 768]);
            int ci = (mt*2 + ut)*4 + r;
            float cn = sigm(gf)*c[ci] + sigm(gi)*tanh_f(gg);
            float hn = sigm(go)*tanh_f(cn);
            c[ci] = cn;
            short hb = f2bf(hn);
            int ls = (s & 15) + 16*(ut*2 + (lr >> 3));
            hfrag[((mt*8 + w)*64 + ls)*8 + (lr & 7)] = hb;
            long grow = (long)t*NS + s0 + s;
            if (y_bf)  y_bf[grow*256 + u]  = hb;
            if (y_f32) y_f32[grow*256 + u] = hn;
            if (t == T-1){
              if (hfin_bf)  hfin_bf[(long)(s0+s)*256 + u]  = hb;
              if (hfin_f32) hfin_f32[(long)(s0+s)*256 + u] = hn;
            }
          }
        }
      }
    }
    // --- write staged G(t+1) into the other LDS buffer (late) ---
    {
      short* dst = gbuf[(t+1)&1];
      #pragma unroll
      for (int k = 0; k < 8; ++k)
        *(short8*)&dst[sr*GSTRIDE + sc + k*128] = gst[k];
    }
    __syncthreads();
  }
}

// ---------------- small flat GEMM (day path): C[M,N]=A@Bt^T+bias ---------
template<bool A_F32>
__global__ __launch_bounds__(256) void k_gemm_flat(
    const void* __restrict__ Av, const short* __restrict__ Bt,
    const float* __restrict__ bias, short* __restrict__ C,
    int M, int N, int Kp, int Ka)
{
  int w = threadIdx.x >> 6, l = threadIdx.x & 63;
  int m0 = blockIdx.x*128 + w*32;
  int n0 = blockIdx.y*128;
  int lr = l & 15, lg = l >> 4;
  f4 acc[2][8];
  #pragma unroll
  for (int i=0;i<2;++i)
    #pragma unroll
    for (int j=0;j<8;++j) acc[i][j] = (f4){0.f,0.f,0.f,0.f};
  const short* Ab = (const short*)Av;
  int nkt = Kp >> 5;
  for (int kt = 0; kt < nkt; ++kt){
    int kb = kt*32 + lg*8;
    short8 a[2];
    #pragma unroll
    for (int mt = 0; mt < 2; ++mt){
      int m = m0 + mt*16 + lr;
      short8 av = {0,0,0,0,0,0,0,0};
      if (m < M) av = *(const short8*)(Ab + (long)m*Kp + kb);
      a[mt] = av;
    }
    #pragma unroll
    for (int nt = 0; nt < 8; ++nt){
      short8 b = *(const short8*)(Bt + (long)(n0 + nt*16 + lr)*Kp + kb);
      acc[0][nt] = mfma16(a[0], b, acc[0][nt]);
      acc[1][nt] = mfma16(a[1], b, acc[1][nt]);
    }
  }
  #pragma unroll
  for (int nt = 0; nt < 8; ++nt){
    int col = n0 + nt*16 + lr;
    float bv = bias ? bias[col] : 0.f;
    #pragma unroll
    for (int mt = 0; mt < 2; ++mt){
      #pragma unroll
      for (int r = 0; r < 4; ++r){
        int row = m0 + mt*16 + lg*4 + r;
        if (row < M) C[(long)row*N + col] = f2bf(acc[mt][nt][r] + bv);
      }
    }
  }
}

// ---------------- day LSTM (batch=1, hidden 64, gates 256), 1 block ------
__global__ __launch_bounds__(1024) void k_day_lstm(
    const short* __restrict__ Gd,   // [T,256] bf16 (inproj+bias)
    const float* __restrict__ Whh,  // [256,64] fp32
    short* __restrict__ y_bf,       // opt [T,64]
    float* __restrict__ y_f32,      // opt [T,64]
    float* __restrict__ hT_f32,     // opt [64]
    int T)
{
  __shared__ float whhT[64*257];
  __shared__ float h[64], cc[64], part[4][256], gates[256];
  int tid = threadIdx.x;
  for (int i = tid; i < 256*64; i += 1024){
    int n = i >> 6, k = i & 63;
    whhT[k*257 + n] = Whh[i];
  }
  if (tid < 64){ h[tid]=0.f; cc[tid]=0.f; }
  __syncthreads();
  int n = tid & 255, kg = tid >> 8;
  for (int t = 0; t < T; ++t){
    float p = 0.f;
    #pragma unroll
    for (int kk = 0; kk < 16; ++kk){
      int k = kg*16 + kk;
      p += h[k]*whhT[k*257+n];
    }
    part[kg][n] = p;
    __syncthreads();
    if (tid < 256)
      gates[tid] = b2f(Gd[t*256+tid]) + part[0][tid]+part[1][tid]+part[2][tid]+part[3][tid];
    __syncthreads();
    if (tid < 64){
      float gi=gates[tid], gf=gates[64+tid], gg=gates[128+tid], go=gates[192+tid];
      float cn = sigm(gf)*cc[tid] + sigm(gi)*tanh_f(gg);
      float hn = sigm(go)*tanh_f(cn);
      cc[tid]=cn; h[tid]=hn;
      if (y_bf)  y_bf[t*64+tid]  = f2bf(hn);
      if (y_f32) y_f32[t*64+tid] = hn;
      if (hT_f32 && t==T-1) hT_f32[tid] = hn;
    }
    __syncthreads();
  }
}

// ---------------- per-day topic attention (truncated top-p 0.8) ----------
// y1 layout [t][30][256] f32.
__global__ __launch_bounds__(256) void k_topic_attn(
    const float* __restrict__ y1, const float* __restrict__ hT,
    const float* __restrict__ w1W, const float* __restrict__ w1b,
    short* __restrict__ dayh)
{
  int d = blockIdx.x, tid = threadIdx.x;
  __shared__ float hf[256], red[4], sc[20], wk[20], c0s;
  hf[tid] = hT[d*256+tid];
  __syncthreads();
  float v = 0.f;
  for (int j=0;j<256;++j) v += hf[j]*w1W[j*256+tid];
  float p0 = w1b[tid]*hf[tid];
  #pragma unroll
  for (int o=32;o>0;o>>=1) p0 += __shfl_down(p0,o);
  if ((tid&63)==0) red[tid>>6] = p0;
  __syncthreads();
  if (tid==0) c0s = red[0]+red[1]+red[2]+red[3];
  __syncthreads();
  for (int t=0;t<20;++t){
    float p = y1[(t*30 + d)*256 + tid]*v;
    #pragma unroll
    for (int o=32;o>0;o>>=1) p += __shfl_down(p,o);
    if ((tid&63)==0) red[tid>>6] = p;
    __syncthreads();
    if (tid==0) sc[t] = red[0]+red[1]+red[2]+red[3] + c0s;
    __syncthreads();
  }
  if (tid==0){
    float mx = -1e30f;
    for (int t=0;t<20;++t) mx = fmaxf(mx, sc[t]);
    float ss = 0.f;
    for (int t=0;t<20;++t){ sc[t] = __expf(sc[t]-mx); ss += sc[t]; }
    float inv = 1.f/ss;
    for (int t=0;t<20;++t) sc[t] *= inv;
    for (int t=0;t<20;++t){
      float pref = 0.f;
      for (int q=0;q<20;++q)
        if (sc[q]>sc[t] || (sc[q]==sc[t] && q<t)) pref += sc[q];
      wk[t] = (pref <= 0.8f) ? sc[t] : 0.f;
    }
  }
  __syncthreads();
  float a = 0.f;
  for (int t=0;t<20;++t) a += wk[t]*y1[(t*30 + d)*256 + tid];
  dayh[d*256+tid] = f2bf(a);
}

// ---------------- final: day attention + linears + head ------------------
__global__ __launch_bounds__(64) void k_final(
    const float* __restrict__ y1,  const float* __restrict__ hT,
    const float* __restrict__ w2W, const float* __restrict__ w2b,
    const float* __restrict__ l1W, const float* __restrict__ l1b,
    const float* __restrict__ l2W, const float* __restrict__ l2b,
    const float* __restrict__ hW,  const float* __restrict__ hb,
    const float* __restrict__ prev, float* __restrict__ out)
{
  int tid = threadIdx.x;
  __shared__ float hf[64], v2[64], sc[30], ctx[64], h1[48], h2[16], c0s;
  hf[tid] = hT[tid];
  __syncthreads();
  { float v=0.f; for (int j=0;j<64;++j) v += hf[j]*w2W[j*64+tid]; v2[tid]=v; }
  if (tid==0){ float c0=0.f; for (int j=0;j<64;++j) c0 += w2b[j]*hf[j]; c0s=c0; }
  __syncthreads();
  if (tid<30){ float sacc=c0s; for (int k=0;k<64;++k) sacc += y1[tid*64+k]*v2[k]; sc[tid]=sacc; }
  __syncthreads();
  if (tid==0){
    float mx=-1e30f; for (int d=0;d<30;++d) mx=fmaxf(mx,sc[d]);
    float ss=0.f; for (int d=0;d<30;++d){ sc[d]=__expf(sc[d]-mx); ss+=sc[d]; }
    float inv=1.f/ss; for (int d=0;d<30;++d) sc[d]*=inv;
  }
  __syncthreads();
  { float cx=0.f; for (int d=0;d<30;++d) cx += sc[d]*y1[d*64+tid]; ctx[tid]=cx; }
  __syncthreads();
  if (tid<48){ float sacc=l1b[tid]; for (int k=0;k<64;++k) sacc += ctx[k]*l1W[tid*64+k]; h1[tid]=sacc; }
  __syncthreads();
  if (tid<16){ float sacc=l2b[tid]; for (int k=0;k<48;++k) sacc += h1[k]*l2W[tid*48+k]; h2[tid]=sacc; }
  __syncthreads();
  if (tid<4){
    float sacc = hb[tid];
    for (int cI=0;cI<16;++cI) sacc += h2[cI]*hW[tid*20+cI];
    for (int cI=0;cI<4; ++cI) sacc += prev[tid*4+cI]*hW[tid*20+16+cI];
    out[tid] = sacc;
  }
}

// ========================================================================
extern "C" void kernel_launch(void* const* d_in, const int* in_sizes, int n_in,
                              void* d_out, int out_size, void* d_ws, size_t ws_size,
                              hipStream_t stream)
{
  const float* X        = (const float*)d_in[0];   // [30,20,128,300]
  const float* prev     = (const float*)d_in[1];
  const float* tWih0    = (const float*)d_in[2];   // [1024,300]
  const float* tWhh0    = (const float*)d_in[3];   // [1024,256]
  const float* tb0      = (const float*)d_in[4];
  // d_in[5..7] text layer-1: DEAD
  const float* pWih0    = (const float*)d_in[8];
  const float* pWhh0    = (const float*)d_in[9];
  const float* pb0      = (const float*)d_in[10];
  const float* pWih1    = (const float*)d_in[11];
  const float* pWhh1    = (const float*)d_in[12];
  const float* pb1      = (const float*)d_in[13];
  const float* dWih0    = (const float*)d_in[14];
  const float* dWhh0    = (const float*)d_in[15];
  const float* db0      = (const float*)d_in[16];
  const float* dWih1    = (const float*)d_in[17];
  const float* dWhh1    = (const float*)d_in[18];
  const float* db1      = (const float*)d_in[19];
  const float* w1W      = (const float*)d_in[20];
  const float* w1b      = (const float*)d_in[21];
  const float* w2W      = (const float*)d_in[22];
  const float* w2b      = (const float*)d_in[23];
  const float* l1W      = (const float*)d_in[24];
  const float* l1b      = (const float*)d_in[25];
  const float* l2W      = (const float*)d_in[26];
  const float* l2b      = (const float*)d_in[27];
  const float* hW       = (const float*)d_in[28];
  const float* hb       = (const float*)d_in[29];
  float* out = (float*)d_out;

  char* wsb = (char*)d_ws;
  size_t off = 0;
  auto alloc = [&](size_t bytes)->void*{
    void* p = wsb + off;
    off = (off + bytes + 255) & ~(size_t)255;
    return p;
  };
  short* G0      = (short*)alloc((size_t)128*600*1024*2);  // [t][seq][1024]
  short* W4tWih  = (short*)alloc((size_t)1024*320*2);
  short* W4tWhh  = (short*)alloc((size_t)1024*256*2);
  short* W4p0i   = (short*)alloc((size_t)1024*256*2);
  short* W4p0h   = (short*)alloc((size_t)1024*256*2);
  short* W4p1i   = (short*)alloc((size_t)1024*256*2);
  short* W4p1h   = (short*)alloc((size_t)1024*256*2);
  short* dW0i    = (short*)alloc((size_t)256*256*2);
  short* dW1i    = (short*)alloc((size_t)256*64*2);
  short* h_text  = (short*)alloc((size_t)600*256*2);       // [seq][256]
  short* Gt0     = (short*)alloc((size_t)20*30*1024*2);    // [t][d][1024]
  short* y_t0    = (short*)alloc((size_t)20*30*256*2);     // [t][d][256]
  float* h_topf  = (float*)alloc((size_t)30*256*4);
  short* Gt1     = (short*)alloc((size_t)20*30*1024*2);
  float* y_t1f   = (float*)alloc((size_t)20*30*256*4);
  short* dayh    = (short*)alloc((size_t)30*256*2);
  short* Gd0     = (short*)alloc((size_t)30*256*2);
  short* y_d0    = (short*)alloc((size_t)30*64*2);
  float* h_d0f   = (float*)alloc((size_t)64*4);
  short* Gd1     = (short*)alloc((size_t)30*256*2);
  float* y_d1f   = (float*)alloc((size_t)30*64*4);
  (void)ws_size; (void)in_sizes; (void)n_in; (void)out_size;

  // --- weight conversions ---
  k_cvt_repack<<<256,256,0,stream>>>(tWih0, W4tWih, 1024, 300, 10);
  k_cvt_repack<<<256,256,0,stream>>>(tWhh0, W4tWhh, 1024, 256, 8);
  k_cvt_repack<<<256,256,0,stream>>>(pWih0, W4p0i, 1024, 256, 8);
  k_cvt_repack<<<256,256,0,stream>>>(pWhh0, W4p0h, 1024, 256, 8);
  k_cvt_repack<<<256,256,0,stream>>>(pWih1, W4p1i, 1024, 256, 8);
  k_cvt_repack<<<256,256,0,stream>>>(pWhh1, W4p1h, 1024, 256, 8);
  k_cvt_pad<<<256,256,0,stream>>>(dWih0, dW0i, 256, 256, 256);
  k_cvt_pad<<<64,256,0,stream>>>(dWih1, dW1i, 256, 64, 64);

  // --- text L0 input projection: rows s*128+t -> G0[t][s] ---
  k_gemm_big<true,10><<<1200,256,0,stream>>>((const void*)X, W4tWih, tb0, G0,
                                             76800, 300, 128, 600);
  // --- text L0 recurrence: ONE dispatch, 19 blocks x 32 seqs ---
  k_lstm_seq<<<19,512,0,stream>>>(G0, W4tWhh, nullptr, nullptr,
                                  h_text, nullptr, 600, 128);
  // --- topic L0: inproj (rows d*20+t -> Gt0[t][d]) + recurrence ---
  k_gemm_big<false,8><<<10,256,0,stream>>>((const void*)h_text, W4p0i, pb0, Gt0,
                                           600, 256, 20, 30);
  k_lstm_seq<<<1,512,0,stream>>>(Gt0, W4p0h, y_t0, nullptr,
                                 nullptr, h_topf, 30, 20);
  // --- topic L1: inproj (rows t*30+d identity) + recurrence ---
  k_gemm_big<false,8><<<10,256,0,stream>>>((const void*)y_t0, W4p1i, pb1, Gt1,
                                           600, 256, 1, 600);
  k_lstm_seq<<<1,512,0,stream>>>(Gt1, W4p1h, nullptr, y_t1f,
                                 nullptr, nullptr, 30, 20);
  // --- per-day topic attention ---
  k_topic_attn<<<30,256,0,stream>>>(y_t1f, h_topf, w1W, w1b, dayh);
  // --- day LSTM (batch=1) ---
  k_gemm_flat<false><<<dim3(1,2),256,0,stream>>>((const void*)dayh, dW0i, db0, Gd0,
                                                 30, 256, 256, 256);
  k_day_lstm<<<1,1024,0,stream>>>(Gd0, dWhh0, y_d0, nullptr, h_d0f, 30);
  k_gemm_flat<false><<<dim3(1,2),256,0,stream>>>((const void*)y_d0, dW1i, db1, Gd1,
                                                 30, 256, 64, 64);
  k_day_lstm<<<1,1024,0,stream>>>(Gd1, dWhh1, nullptr, y_d1f, nullptr, 30);
  // --- final ---
  k_final<<<1,64,0,stream>>>(y_d1f, h_d0f, w2W, w2b, l1W, l1b, l2W, l2b,
                             hW, hb, prev, out);
}